// Round 3
// baseline (96.074 us; speedup 1.0000x reference)
//
#include <hip/hip_runtime.h>
#include <float.h>

#define Bsz 2048
#define Nn  1024
#define Dd  256

typedef __attribute__((ext_vector_type(8))) short bf16x8;
typedef __attribute__((ext_vector_type(4))) float f32x4;
typedef unsigned long long u64;

// round-to-nearest-even f32 -> bf16 bits
__device__ __forceinline__ unsigned short bfr(float x) {
    unsigned u = __float_as_uint(x);
    u += 0x7fffu + ((u >> 16) & 1u);
    return (unsigned short)(u >> 16);
}
__device__ __forceinline__ float bf2f(unsigned short h) {
    return __uint_as_float(((unsigned)h) << 16);
}

__device__ __forceinline__ void som_params(const int* __restrict__ step,
                                           const int* __restrict__ total,
                                           float* taxa, float* inv2s2) {
    float frac = (float)(*step) / (float)(*total);
    float e = __expf(-frac);
    *taxa = 0.5f * e;
    float sigma = 16.0f * e;              // SIGMA_INICIAL = 16
    *inv2s2 = 1.0f / (2.0f * sigma * sigma);
}

// sortable-u32 encoding of f32 (monotone), packed with index; min => argmin
// with first-index (lowest n) tie-break, matching jnp.argmin.
__device__ __forceinline__ u64 packsc(float f, int n) {
    unsigned u = __float_as_uint(f);
    u = (u & 0x80000000u) ? ~u : (u | 0x80000000u);
    return ((u64)u << 32) | (unsigned)n;
}

// ---------------------------------------------------------------------------
// prep W: hi/lo bf16 split + w2 (one wave per row, 4 rows/block)
// ---------------------------------------------------------------------------
__global__ __launch_bounds__(256) void prep_w(
    const float* __restrict__ W, ushort* __restrict__ hi,
    ushort* __restrict__ lo, float* __restrict__ w2)
{
    int row  = blockIdx.x * 4 + (threadIdx.x >> 6);
    int lane = threadIdx.x & 63;
    float4 v = ((const float4*)(W + (size_t)row * Dd))[lane];
    float s = v.x*v.x + v.y*v.y + v.z*v.z + v.w*v.w;
    #pragma unroll
    for (int m = 32; m; m >>= 1) s += __shfl_xor(s, m, 64);
    if (lane == 0) w2[row] = s;
    ushort4 h, l;
    h.x = bfr(v.x); l.x = bfr(v.x - bf2f(h.x));
    h.y = bfr(v.y); l.y = bfr(v.y - bf2f(h.y));
    h.z = bfr(v.z); l.z = bfr(v.z - bf2f(h.z));
    h.w = bfr(v.w); l.w = bfr(v.w - bf2f(h.w));
    *(ushort4*)&hi[(size_t)row * Dd + lane * 4] = h;
    *(ushort4*)&lo[(size_t)row * Dd + lane * 4] = l;
}

// ---------------------------------------------------------------------------
// prep X: hi/lo split (row-major) + bf16 transpose Xt[d][b] + bmin init
// grid (32 b-tiles, 4 d-tiles), block 256
// ---------------------------------------------------------------------------
__global__ __launch_bounds__(256) void prep_x(
    const float* __restrict__ X, ushort* __restrict__ Xhi,
    ushort* __restrict__ Xlo, ushort* __restrict__ Xt,
    u64* __restrict__ bmin)
{
    __shared__ float ld[64][65];
    const int t  = threadIdx.x;
    const int b0 = blockIdx.x * 64;
    const int d0 = blockIdx.y * 64;

    if (blockIdx.y == 0 && t < 64) bmin[b0 + t] = ~0ull;

    #pragma unroll
    for (int p = 0; p < 4; ++p) {
        int flat = p * 256 + t;
        int row = flat >> 4, c4 = flat & 15;
        float4 v = *(const float4*)&X[(size_t)(b0 + row) * Dd + d0 + c4 * 4];
        ushort4 h, l;
        h.x = bfr(v.x); l.x = bfr(v.x - bf2f(h.x));
        h.y = bfr(v.y); l.y = bfr(v.y - bf2f(h.y));
        h.z = bfr(v.z); l.z = bfr(v.z - bf2f(h.z));
        h.w = bfr(v.w); l.w = bfr(v.w - bf2f(h.w));
        size_t off = (size_t)(b0 + row) * Dd + d0 + c4 * 4;
        *(ushort4*)&Xhi[off] = h;
        *(ushort4*)&Xlo[off] = l;
        ld[row][c4*4+0] = v.x; ld[row][c4*4+1] = v.y;
        ld[row][c4*4+2] = v.z; ld[row][c4*4+3] = v.w;
    }
    __syncthreads();
    #pragma unroll
    for (int q = 0; q < 2; ++q) {
        int idx = q * 256 + t;
        int d = idx >> 3;             // 0..63 d-local
        int bs = (idx & 7) * 8;       // b-local chunk of 8
        bf16x8 o;
        #pragma unroll
        for (int j = 0; j < 8; ++j) o[j] = (short)bfr(ld[bs + j][d]);
        *(bf16x8*)&Xt[(size_t)(d0 + d) * Bsz + b0 + bs] = o;
    }
}

// ---------------------------------------------------------------------------
// BMU: score[b][n] = w2[n] - 2*dot(X[b],W[n]) via hi/lo-split MFMA;
// packed atomicMin(u64) -> bmin[b].  grid (16 b-tiles of 128, 16 n-tiles of 64)
// 4 waves: wm=b-half, wn=n-half; wave tile 64b x 32n
// ---------------------------------------------------------------------------
__global__ __launch_bounds__(256) void bmu_mfma(
    const ushort* __restrict__ Xhi, const ushort* __restrict__ Xlo,
    const ushort* __restrict__ Whi, const ushort* __restrict__ Wlo,
    const float* __restrict__ w2, u64* __restrict__ bmin)
{
    const int t = threadIdx.x, w = t >> 6, l = t & 63;
    const int wm = w & 1, wn = w >> 1;
    const int b0 = blockIdx.x * 128 + wm * 64;
    const int n0 = blockIdx.y * 64 + wn * 32;
    const int lr = l & 15, lg = l >> 4;

    f32x4 acc[4][2];
    #pragma unroll
    for (int m = 0; m < 4; ++m)
        #pragma unroll
        for (int n = 0; n < 2; ++n) { f32x4 z = {0.f,0.f,0.f,0.f}; acc[m][n] = z; }

    for (int kd = 0; kd < Dd; kd += 32) {
        bf16x8 ah[4], al[4], bh[2], bl[2];
        #pragma unroll
        for (int m = 0; m < 4; ++m) {
            size_t off = (size_t)(b0 + m*16 + lr) * Dd + kd + lg*8;
            ah[m] = *(const bf16x8*)&Xhi[off];
            al[m] = *(const bf16x8*)&Xlo[off];
        }
        #pragma unroll
        for (int n = 0; n < 2; ++n) {
            size_t off = (size_t)(n0 + n*16 + lr) * Dd + kd + lg*8;
            bh[n] = *(const bf16x8*)&Whi[off];
            bl[n] = *(const bf16x8*)&Wlo[off];
        }
        #pragma unroll
        for (int m = 0; m < 4; ++m)
            #pragma unroll
            for (int n = 0; n < 2; ++n) {
                acc[m][n] = __builtin_amdgcn_mfma_f32_16x16x32_bf16(ah[m], bh[n], acc[m][n], 0, 0, 0);
                acc[m][n] = __builtin_amdgcn_mfma_f32_16x16x32_bf16(ah[m], bl[n], acc[m][n], 0, 0, 0);
                acc[m][n] = __builtin_amdgcn_mfma_f32_16x16x32_bf16(al[m], bh[n], acc[m][n], 0, 0, 0);
            }
    }

    float w2v[2]; int nidx[2];
    #pragma unroll
    for (int n = 0; n < 2; ++n) { nidx[n] = n0 + n*16 + lr; w2v[n] = w2[nidx[n]]; }

    #pragma unroll
    for (int m = 0; m < 4; ++m)
        #pragma unroll
        for (int r = 0; r < 4; ++r) {
            u64 p0 = packsc(w2v[0] - 2.f * acc[m][0][r], nidx[0]);
            u64 p1 = packsc(w2v[1] - 2.f * acc[m][1][r], nidx[1]);
            u64 pm = p1 < p0 ? p1 : p0;
            // reduce across the 16 lr lanes (lg constant within group)
            #pragma unroll
            for (int msk = 1; msk < 16; msk <<= 1) {
                unsigned lo = (unsigned)pm, hi = (unsigned)(pm >> 32);
                lo = __shfl_xor(lo, msk, 64);
                hi = __shfl_xor(hi, msk, 64);
                u64 o = ((u64)hi << 32) | lo;
                if (o < pm) pm = o;
            }
            if (lr == 0) {
                int b = b0 + m*16 + lg*4 + r;
                atomicMin(&bmin[b], pm);
            }
        }
}

// ---------------------------------------------------------------------------
// hgen: Ht[n][b] = bf16(h), hsum[n] = sum_b h.  one block per n (grid 1024)
// grid coords derived from indices: loc[k] = (k%32, k//32)  (meshgrid 'xy')
// ---------------------------------------------------------------------------
__global__ __launch_bounds__(256) void hgen(
    const u64* __restrict__ bmin, const int* __restrict__ step,
    const int* __restrict__ total, ushort* __restrict__ Ht,
    float* __restrict__ hsum)
{
    const int n = blockIdx.x, t = threadIdx.x;
    float taxa, inv2s2;
    som_params(step, total, &taxa, &inv2s2);
    const int nx = n & 31, ny = n >> 5;

    float part = 0.f;
    bf16x8 o;
    #pragma unroll
    for (int j = 0; j < 8; ++j) {
        unsigned idx = (unsigned)(bmin[t*8 + j] & 0xffffffffu);
        int dx = nx - (int)(idx & 31);
        int dy = ny - (int)(idx >> 5);
        float h = __expf(-(float)(dx*dx + dy*dy) * inv2s2);
        o[j] = (short)bfr(h);
        part += h;
    }
    *(bf16x8*)&Ht[(size_t)n * Bsz + t*8] = o;

    #pragma unroll
    for (int m = 1; m < 64; m <<= 1) part += __shfl_xor(part, m, 64);
    __shared__ float ws[4];
    if ((t & 63) == 0) ws[t >> 6] = part;
    __syncthreads();
    if (t == 0) hsum[n] = ws[0] + ws[1] + ws[2] + ws[3];
}

// ---------------------------------------------------------------------------
// acc+finish fused: out[n][d] = W + taxa*((Ht@X)[n][d] - hsum[n]*W)/B
// grid 32 (n-tiles of 32); block 512 = 8 waves, wave w owns d-slice w*32
// ---------------------------------------------------------------------------
__global__ __launch_bounds__(512) void acc_finish(
    const ushort* __restrict__ Ht, const ushort* __restrict__ Xt,
    const float* __restrict__ hsum, const float* __restrict__ W,
    const int* __restrict__ step, const int* __restrict__ total,
    float* __restrict__ out)
{
    const int t = threadIdx.x, w = t >> 6, l = t & 63;
    const int lr = l & 15, lg = l >> 4;
    const int n0 = blockIdx.x * 32;
    const int d0 = w * 32;

    float taxa, inv2s2;
    som_params(step, total, &taxa, &inv2s2);
    const float invB = 1.0f / 2048.0f;

    f32x4 acc[2][2];
    #pragma unroll
    for (int m = 0; m < 2; ++m)
        #pragma unroll
        for (int nf = 0; nf < 2; ++nf) { f32x4 z = {0.f,0.f,0.f,0.f}; acc[m][nf] = z; }

    for (int ks = 0; ks < 64; ++ks) {
        const int bk = ks*32 + lg*8;
        bf16x8 am[2], bx[2];
        #pragma unroll
        for (int m = 0; m < 2; ++m)
            am[m] = *(const bf16x8*)&Ht[(size_t)(n0 + m*16 + lr) * Bsz + bk];
        #pragma unroll
        for (int nf = 0; nf < 2; ++nf)
            bx[nf] = *(const bf16x8*)&Xt[(size_t)(d0 + nf*16 + lr) * Bsz + bk];
        #pragma unroll
        for (int m = 0; m < 2; ++m)
            #pragma unroll
            for (int nf = 0; nf < 2; ++nf)
                acc[m][nf] = __builtin_amdgcn_mfma_f32_16x16x32_bf16(am[m], bx[nf], acc[m][nf], 0, 0, 0);
    }

    #pragma unroll
    for (int m = 0; m < 2; ++m)
        #pragma unroll
        for (int r = 0; r < 4; ++r) {
            int n = n0 + m*16 + lg*4 + r;
            float hsn = hsum[n];
            #pragma unroll
            for (int nf = 0; nf < 2; ++nf) {
                int d = d0 + nf*16 + lr;
                float wv = W[(size_t)n * Dd + d];
                out[(size_t)n * Dd + d] = wv + taxa * (acc[m][nf][r] - hsn * wv) * invB;
            }
        }
}

// ---------------------------------------------------------------------------
extern "C" void kernel_launch(void* const* d_in, const int* in_sizes, int n_in,
                              void* d_out, int out_size, void* d_ws, size_t ws_size,
                              hipStream_t stream)
{
    const float* X    = (const float*)d_in[0];
    const float* W    = (const float*)d_in[1];
    const int* step   = (const int*)d_in[3];
    const int* total  = (const int*)d_in[4];
    float* out = (float*)d_out;

    // workspace (~5.05 MB): small | Xt | region A (phase1: X/W splits, 3 MB)
    // Ht (4 MB) ALIASES region A — written by hgen only after bmu_mfma (the
    // sole consumer of the splits) has completed (same-stream ordering).
    char* p = (char*)d_ws;
    float* w2   = (float*)p;  p += 4096;
    u64*   bmin = (u64*)p;    p += 16384;
    float* hsum = (float*)p;  p += 4096;
    ushort* Xt  = (ushort*)p; p += 1048576;
    char* regA = p;
    ushort* Xhi = (ushort*)regA;
    ushort* Xlo = (ushort*)(regA + 1048576);
    ushort* Whi = (ushort*)(regA + 2097152);
    ushort* Wlo = (ushort*)(regA + 2621440);
    ushort* Ht  = (ushort*)regA;              // 4 MB, aliases splits

    prep_w    <<<256, 256, 0, stream>>>(W, Whi, Wlo, w2);
    prep_x    <<<dim3(32, 4), 256, 0, stream>>>(X, Xhi, Xlo, Xt, bmin);
    bmu_mfma  <<<dim3(16, 16), 256, 0, stream>>>(Xhi, Xlo, Whi, Wlo, w2, bmin);
    hgen      <<<1024, 256, 0, stream>>>(bmin, step, total, Ht, hsum);
    acc_finish<<<32, 512, 0, stream>>>(Ht, Xt, hsum, W, step, total, out);
}

// Round 4
// 44.325 us; speedup vs baseline: 2.1675x; 2.1675x over previous
//
#include <hip/hip_runtime.h>
#include <float.h>

#define Bsz 2048
#define Nn  1024
#define Dd  256

typedef __attribute__((ext_vector_type(8))) short bf16x8;
typedef __attribute__((ext_vector_type(4))) float f32x4;
typedef unsigned long long u64;

// round-to-nearest-even f32 -> bf16 bits
__device__ __forceinline__ unsigned short bfr(float x) {
    unsigned u = __float_as_uint(x);
    u += 0x7fffu + ((u >> 16) & 1u);
    return (unsigned short)(u >> 16);
}
__device__ __forceinline__ float bf2f(unsigned short h) {
    return __uint_as_float(((unsigned)h) << 16);
}

__device__ __forceinline__ void som_params(const int* __restrict__ step,
                                           const int* __restrict__ total,
                                           float* taxa, float* inv2s2) {
    float frac = (float)(*step) / (float)(*total);
    float e = __expf(-frac);
    *taxa = 0.5f * e;
    float sigma = 16.0f * e;              // SIGMA_INICIAL = 16
    *inv2s2 = 1.0f / (2.0f * sigma * sigma);
}

// sortable-u32 encoding of f32 (monotone), packed with index; min => argmin
// with first-index (lowest n) tie-break, matching jnp.argmin.
__device__ __forceinline__ u64 packsc(float f, int n) {
    unsigned u = __float_as_uint(f);
    u = (u & 0x80000000u) ? ~u : (u | 0x80000000u);
    return ((u64)u << 32) | (unsigned)n;
}

// ---------------------------------------------------------------------------
// prep W: hi/lo bf16 split + w2 (one wave per row, 4 rows/block)
// ---------------------------------------------------------------------------
__global__ __launch_bounds__(256) void prep_w(
    const float* __restrict__ W, ushort* __restrict__ hi,
    ushort* __restrict__ lo, float* __restrict__ w2)
{
    int row  = blockIdx.x * 4 + (threadIdx.x >> 6);
    int lane = threadIdx.x & 63;
    float4 v = ((const float4*)(W + (size_t)row * Dd))[lane];
    float s = v.x*v.x + v.y*v.y + v.z*v.z + v.w*v.w;
    #pragma unroll
    for (int m = 32; m; m >>= 1) s += __shfl_xor(s, m, 64);
    if (lane == 0) w2[row] = s;
    ushort4 h, l;
    h.x = bfr(v.x); l.x = bfr(v.x - bf2f(h.x));
    h.y = bfr(v.y); l.y = bfr(v.y - bf2f(h.y));
    h.z = bfr(v.z); l.z = bfr(v.z - bf2f(h.z));
    h.w = bfr(v.w); l.w = bfr(v.w - bf2f(h.w));
    *(ushort4*)&hi[(size_t)row * Dd + lane * 4] = h;
    *(ushort4*)&lo[(size_t)row * Dd + lane * 4] = l;
}

// ---------------------------------------------------------------------------
// prep X: hi/lo split (row-major) + bf16 transpose Xt[d][b] + bmin init
// grid (32 b-tiles, 4 d-tiles), block 256
// ---------------------------------------------------------------------------
__global__ __launch_bounds__(256) void prep_x(
    const float* __restrict__ X, ushort* __restrict__ Xhi,
    ushort* __restrict__ Xlo, ushort* __restrict__ Xt,
    u64* __restrict__ bmin)
{
    __shared__ float ld[64][65];
    const int t  = threadIdx.x;
    const int b0 = blockIdx.x * 64;
    const int d0 = blockIdx.y * 64;

    if (blockIdx.y == 0 && t < 64) bmin[b0 + t] = ~0ull;

    #pragma unroll
    for (int p = 0; p < 4; ++p) {
        int flat = p * 256 + t;
        int row = flat >> 4, c4 = flat & 15;
        float4 v = *(const float4*)&X[(size_t)(b0 + row) * Dd + d0 + c4 * 4];
        ushort4 h, l;
        h.x = bfr(v.x); l.x = bfr(v.x - bf2f(h.x));
        h.y = bfr(v.y); l.y = bfr(v.y - bf2f(h.y));
        h.z = bfr(v.z); l.z = bfr(v.z - bf2f(h.z));
        h.w = bfr(v.w); l.w = bfr(v.w - bf2f(h.w));
        size_t off = (size_t)(b0 + row) * Dd + d0 + c4 * 4;
        *(ushort4*)&Xhi[off] = h;
        *(ushort4*)&Xlo[off] = l;
        ld[row][c4*4+0] = v.x; ld[row][c4*4+1] = v.y;
        ld[row][c4*4+2] = v.z; ld[row][c4*4+3] = v.w;
    }
    __syncthreads();
    #pragma unroll
    for (int q = 0; q < 2; ++q) {
        int idx = q * 256 + t;
        int d = idx >> 3;             // 0..63 d-local
        int bs = (idx & 7) * 8;       // b-local chunk of 8
        bf16x8 o;
        #pragma unroll
        for (int j = 0; j < 8; ++j) o[j] = (short)bfr(ld[bs + j][d]);
        *(bf16x8*)&Xt[(size_t)(d0 + d) * Bsz + b0 + bs] = o;
    }
}

// ---------------------------------------------------------------------------
// BMU: score[b][n] = w2[n] - 2*dot(X[b],W[n]) via hi/lo-split MFMA;
// packed atomicMin(u64) -> bmin[b].  grid (16 b-tiles of 128, 16 n-tiles of 64)
// 4 waves: wm=b-half, wn=n-half; wave tile 64b x 32n
// ---------------------------------------------------------------------------
__global__ __launch_bounds__(256) void bmu_mfma(
    const ushort* __restrict__ Xhi, const ushort* __restrict__ Xlo,
    const ushort* __restrict__ Whi, const ushort* __restrict__ Wlo,
    const float* __restrict__ w2, u64* __restrict__ bmin)
{
    const int t = threadIdx.x, w = t >> 6, l = t & 63;
    const int wm = w & 1, wn = w >> 1;
    const int b0 = blockIdx.x * 128 + wm * 64;
    const int n0 = blockIdx.y * 64 + wn * 32;
    const int lr = l & 15, lg = l >> 4;

    f32x4 acc[4][2];
    #pragma unroll
    for (int m = 0; m < 4; ++m)
        #pragma unroll
        for (int n = 0; n < 2; ++n) { f32x4 z = {0.f,0.f,0.f,0.f}; acc[m][n] = z; }

    #pragma unroll
    for (int kd = 0; kd < Dd; kd += 32) {
        bf16x8 ah[4], al[4], bh[2], bl[2];
        #pragma unroll
        for (int m = 0; m < 4; ++m) {
            size_t off = (size_t)(b0 + m*16 + lr) * Dd + kd + lg*8;
            ah[m] = *(const bf16x8*)&Xhi[off];
            al[m] = *(const bf16x8*)&Xlo[off];
        }
        #pragma unroll
        for (int n = 0; n < 2; ++n) {
            size_t off = (size_t)(n0 + n*16 + lr) * Dd + kd + lg*8;
            bh[n] = *(const bf16x8*)&Whi[off];
            bl[n] = *(const bf16x8*)&Wlo[off];
        }
        #pragma unroll
        for (int m = 0; m < 4; ++m)
            #pragma unroll
            for (int n = 0; n < 2; ++n) {
                acc[m][n] = __builtin_amdgcn_mfma_f32_16x16x32_bf16(ah[m], bh[n], acc[m][n], 0, 0, 0);
                acc[m][n] = __builtin_amdgcn_mfma_f32_16x16x32_bf16(ah[m], bl[n], acc[m][n], 0, 0, 0);
                acc[m][n] = __builtin_amdgcn_mfma_f32_16x16x32_bf16(al[m], bh[n], acc[m][n], 0, 0, 0);
            }
    }

    float w2v[2]; int nidx[2];
    #pragma unroll
    for (int n = 0; n < 2; ++n) { nidx[n] = n0 + n*16 + lr; w2v[n] = w2[nidx[n]]; }

    #pragma unroll
    for (int m = 0; m < 4; ++m)
        #pragma unroll
        for (int r = 0; r < 4; ++r) {
            u64 p0 = packsc(w2v[0] - 2.f * acc[m][0][r], nidx[0]);
            u64 p1 = packsc(w2v[1] - 2.f * acc[m][1][r], nidx[1]);
            u64 pm = p1 < p0 ? p1 : p0;
            #pragma unroll
            for (int msk = 1; msk < 16; msk <<= 1) {
                unsigned lo = (unsigned)pm, hi = (unsigned)(pm >> 32);
                lo = __shfl_xor(lo, msk, 64);
                hi = __shfl_xor(hi, msk, 64);
                u64 o = ((u64)hi << 32) | lo;
                if (o < pm) pm = o;
            }
            if (lr == 0) {
                int b = b0 + m*16 + lg*4 + r;
                atomicMin(&bmin[b], pm);
            }
        }
}

// ---------------------------------------------------------------------------
// hgen: Ht[n][b] = bf16(h), hsum[n] = sum_b h.  one block per n (grid 1024)
// grid coords derived from indices: loc[k] = (k%32, k//32)  (meshgrid 'xy')
// ---------------------------------------------------------------------------
__global__ __launch_bounds__(256) void hgen(
    const u64* __restrict__ bmin, const int* __restrict__ step,
    const int* __restrict__ total, ushort* __restrict__ Ht,
    float* __restrict__ hsum)
{
    const int n = blockIdx.x, t = threadIdx.x;
    float taxa, inv2s2;
    som_params(step, total, &taxa, &inv2s2);
    const int nx = n & 31, ny = n >> 5;

    float part = 0.f;
    bf16x8 o;
    #pragma unroll
    for (int j = 0; j < 8; ++j) {
        unsigned idx = (unsigned)(bmin[t*8 + j] & 0xffffffffu);
        int dx = nx - (int)(idx & 31);
        int dy = ny - (int)(idx >> 5);
        float h = __expf(-(float)(dx*dx + dy*dy) * inv2s2);
        o[j] = (short)bfr(h);
        part += h;
    }
    *(bf16x8*)&Ht[(size_t)n * Bsz + t*8] = o;

    #pragma unroll
    for (int m = 1; m < 64; m <<= 1) part += __shfl_xor(part, m, 64);
    __shared__ float ws[4];
    if ((t & 63) == 0) ws[t >> 6] = part;
    __syncthreads();
    if (t == 0) hsum[n] = ws[0] + ws[1] + ws[2] + ws[3];
}

// ---------------------------------------------------------------------------
// acc+finish: out[n][d] = W + taxa*((Ht@X)[n][d] - hsum[n]*W)/B
// grid (32 n-tiles of 32, 8 d-tiles of 32); block 512 = 8 waves.
// Wave w computes the FULL 32x32 tile over its b-chunk of 256 (in-block
// split-K); partials reduced through LDS; epilogue applies the W update.
// ---------------------------------------------------------------------------
__global__ __launch_bounds__(512) void acc_finish(
    const ushort* __restrict__ Ht, const ushort* __restrict__ Xt,
    const float* __restrict__ hsum, const float* __restrict__ W,
    const int* __restrict__ step, const int* __restrict__ total,
    float* __restrict__ out)
{
    __shared__ float red[8][32][36];   // [wave][n][d], +4 pad vs 32-bank

    const int t = threadIdx.x, w = t >> 6, l = t & 63;
    const int lr = l & 15, lg = l >> 4;
    const int n0 = blockIdx.x * 32;
    const int d0 = blockIdx.y * 32;

    f32x4 acc[2][2];
    #pragma unroll
    for (int m = 0; m < 2; ++m)
        #pragma unroll
        for (int nf = 0; nf < 2; ++nf) { f32x4 z = {0.f,0.f,0.f,0.f}; acc[m][nf] = z; }

    #pragma unroll
    for (int ks = 0; ks < 8; ++ks) {
        const int bk = w * 256 + ks * 32 + lg * 8;
        bf16x8 am[2], bx[2];
        #pragma unroll
        for (int m = 0; m < 2; ++m)
            am[m] = *(const bf16x8*)&Ht[(size_t)(n0 + m*16 + lr) * Bsz + bk];
        #pragma unroll
        for (int nf = 0; nf < 2; ++nf)
            bx[nf] = *(const bf16x8*)&Xt[(size_t)(d0 + nf*16 + lr) * Bsz + bk];
        #pragma unroll
        for (int m = 0; m < 2; ++m)
            #pragma unroll
            for (int nf = 0; nf < 2; ++nf)
                acc[m][nf] = __builtin_amdgcn_mfma_f32_16x16x32_bf16(am[m], bx[nf], acc[m][nf], 0, 0, 0);
    }

    // stash per-wave partials
    #pragma unroll
    for (int m = 0; m < 2; ++m)
        #pragma unroll
        for (int nf = 0; nf < 2; ++nf)
            #pragma unroll
            for (int r = 0; r < 4; ++r)
                red[w][m*16 + lg*4 + r][nf*16 + lr] = acc[m][nf][r];
    __syncthreads();

    // reduce 8 waves + fused epilogue: 512 threads x 2 outputs (float2)
    float taxa, inv2s2;
    som_params(step, total, &taxa, &inv2s2);
    const float invB = 1.0f / 2048.0f;

    const int nl = t >> 4;          // 0..31
    const int dl = (t & 15) * 2;    // 0,2,..,30
    float s0 = 0.f, s1 = 0.f;
    #pragma unroll
    for (int ww = 0; ww < 8; ++ww) {
        s0 += red[ww][nl][dl];
        s1 += red[ww][nl][dl + 1];
    }
    const int n = n0 + nl;
    const int d = d0 + dl;
    const float hsn = hsum[n];
    const float* wp = &W[(size_t)n * Dd + d];
    float wv0 = wp[0], wv1 = wp[1];
    float o0 = wv0 + taxa * (s0 - hsn * wv0) * invB;
    float o1 = wv1 + taxa * (s1 - hsn * wv1) * invB;
    float2 o = make_float2(o0, o1);
    *(float2*)&out[(size_t)n * Dd + d] = o;
}

// ---------------------------------------------------------------------------
extern "C" void kernel_launch(void* const* d_in, const int* in_sizes, int n_in,
                              void* d_out, int out_size, void* d_ws, size_t ws_size,
                              hipStream_t stream)
{
    const float* X    = (const float*)d_in[0];
    const float* W    = (const float*)d_in[1];
    const int* step   = (const int*)d_in[3];
    const int* total  = (const int*)d_in[4];
    float* out = (float*)d_out;

    // workspace (~5.07 MB): small | Xt | region A (phase1: X/W splits, 3 MB)
    // Ht (4 MB) ALIASES region A — written by hgen only after bmu_mfma (the
    // sole consumer of the splits) has completed (same-stream ordering).
    char* p = (char*)d_ws;
    float* w2   = (float*)p;  p += 4096;
    u64*   bmin = (u64*)p;    p += 16384;
    float* hsum = (float*)p;  p += 4096;
    ushort* Xt  = (ushort*)p; p += 1048576;
    char* regA = p;
    ushort* Xhi = (ushort*)regA;
    ushort* Xlo = (ushort*)(regA + 1048576);
    ushort* Whi = (ushort*)(regA + 2097152);
    ushort* Wlo = (ushort*)(regA + 2621440);
    ushort* Ht  = (ushort*)regA;              // 4 MB, aliases splits

    prep_w    <<<256, 256, 0, stream>>>(W, Whi, Wlo, w2);
    prep_x    <<<dim3(32, 4), 256, 0, stream>>>(X, Xhi, Xlo, Xt, bmin);
    bmu_mfma  <<<dim3(16, 16), 256, 0, stream>>>(Xhi, Xlo, Whi, Wlo, w2, bmin);
    hgen      <<<1024, 256, 0, stream>>>(bmin, step, total, Ht, hsum);
    acc_finish<<<dim3(32, 8), 512, 0, stream>>>(Ht, Xt, hsum, W, step, total, out);
}